// Round 1
// baseline (5862.163 us; speedup 1.0000x reference)
//
#include <hip/hip_runtime.h>

#define N_NODES 10000
#define E_EDGES 320000
#define HDIM    256
#define NG      20
#define BN_EPS  1e-5f
#define EB      16   // edges per block (E_EDGES/EB = 20000 exact)
#define RB      16   // rows per block  (N_NODES/RB = 625 exact)

__device__ __forceinline__ float silu_f(float v) {
    return v / (1.0f + __expf(-v));
}

// ---------------------------------------------------------------------------
// Edge kernel: per block, 16 edges.
//   hidden = silu(rbf @ Wf1 + bf1)           [EB,256] in LDS
//   filt   = hidden @ Wf2 + bf2              per-thread 16 cols
//   msg    = x[col] * filt ; atomicAdd into agg[row]
// ---------------------------------------------------------------------------
__global__ __launch_bounds__(256) void edge_kernel(
    const float* __restrict__ x, const float* __restrict__ rbf,
    const int* __restrict__ ei,
    const float* __restrict__ Wf1, const float* __restrict__ bf1,
    const float* __restrict__ Wf2, const float* __restrict__ bf2,
    float* __restrict__ agg)
{
    __shared__ float rbf_lds[EB * NG];
    __shared__ float hid_lds[EB * 257];   // +1 pad: stride-256 would 4-way conflict
    __shared__ int   row_lds[EB];
    __shared__ int   col_lds[EB];

    const int t  = threadIdx.x;
    const int e0 = blockIdx.x * EB;

    // stage rbf tile (contiguous, coalesced) + edge indices
    for (int i = t; i < EB * NG; i += 256) rbf_lds[i] = rbf[e0 * NG + i];
    if (t < EB) {
        row_lds[t] = ei[e0 + t];
        col_lds[t] = ei[E_EDGES + e0 + t];
    }
    __syncthreads();

    // hidden = silu(rbf @ Wf1 + bf1): thread t owns column j=t
    {
        const int j = t;
        float w[NG];
        #pragma unroll
        for (int k = 0; k < NG; ++k) w[k] = Wf1[k * HDIM + j];
        const float b = bf1[j];
        #pragma unroll 4
        for (int e = 0; e < EB; ++e) {
            float acc = b;
            #pragma unroll
            for (int k = 0; k < NG; ++k) acc += rbf_lds[e * NG + k] * w[k];
            hid_lds[e * 257 + j] = silu_f(acc);
        }
    }
    __syncthreads();

    // filt = hidden @ Wf2 + bf2 ; msg ; scatter
    const int e  = t >> 4;
    const int j0 = (t & 15) << 4;

    float acc[16];
    #pragma unroll
    for (int i = 0; i < 16; ++i) acc[i] = 0.0f;

    const float* hrow = &hid_lds[e * 257];
    for (int k = 0; k < HDIM; ++k) {
        const float hv = hrow[k];
        const float4* wr = reinterpret_cast<const float4*>(Wf2 + (k << 8) + j0);
        const float4 a = wr[0], b = wr[1], c = wr[2], d = wr[3];
        acc[ 0] += hv * a.x; acc[ 1] += hv * a.y; acc[ 2] += hv * a.z; acc[ 3] += hv * a.w;
        acc[ 4] += hv * b.x; acc[ 5] += hv * b.y; acc[ 6] += hv * b.z; acc[ 7] += hv * b.w;
        acc[ 8] += hv * c.x; acc[ 9] += hv * c.y; acc[10] += hv * c.z; acc[11] += hv * c.w;
        acc[12] += hv * d.x; acc[13] += hv * d.y; acc[14] += hv * d.z; acc[15] += hv * d.w;
    }

    const int r = row_lds[e];
    const int c = col_lds[e];
    const float4* xr = reinterpret_cast<const float4*>(x + c * HDIM + j0);
    const float4 x0 = xr[0], x1 = xr[1], x2 = xr[2], x3 = xr[3];
    float xv[16] = { x0.x, x0.y, x0.z, x0.w, x1.x, x1.y, x1.z, x1.w,
                     x2.x, x2.y, x2.z, x2.w, x3.x, x3.y, x3.z, x3.w };

    float* aggp = agg + r * HDIM + j0;
    #pragma unroll
    for (int i = 0; i < 16; ++i) {
        const float msg = (acc[i] + bf2[j0 + i]) * xv[i];
        atomicAdd(aggp + i, msg);
    }
}

// ---------------------------------------------------------------------------
// Node kernel: h = silu(agg @ Wu1 + bu1) @ Wu2 + bu2   -> h_out (=d_out temp)
// ---------------------------------------------------------------------------
__global__ __launch_bounds__(256) void node_kernel(
    const float* __restrict__ agg,
    const float* __restrict__ Wu1, const float* __restrict__ bu1,
    const float* __restrict__ Wu2, const float* __restrict__ bu2,
    float* __restrict__ h_out)
{
    __shared__ float a_lds[RB * 257];
    __shared__ float m_lds[RB * 257];

    const int t  = threadIdx.x;
    const int r0 = blockIdx.x * RB;

    for (int i = t; i < RB * HDIM; i += 256) {
        const int rr = i >> 8, cc = i & 255;
        a_lds[rr * 257 + cc] = agg[(r0 + rr) * HDIM + cc];
    }
    __syncthreads();

    const int rr = t >> 4;
    const int j0 = (t & 15) << 4;

    // mid = silu(agg @ Wu1 + bu1)
    float acc[16];
    #pragma unroll
    for (int i = 0; i < 16; ++i) acc[i] = bu1[j0 + i];
    {
        const float* arow = &a_lds[rr * 257];
        for (int k = 0; k < HDIM; ++k) {
            const float av = arow[k];
            const float4* wr = reinterpret_cast<const float4*>(Wu1 + (k << 8) + j0);
            const float4 a = wr[0], b = wr[1], c = wr[2], d = wr[3];
            acc[ 0] += av * a.x; acc[ 1] += av * a.y; acc[ 2] += av * a.z; acc[ 3] += av * a.w;
            acc[ 4] += av * b.x; acc[ 5] += av * b.y; acc[ 6] += av * b.z; acc[ 7] += av * b.w;
            acc[ 8] += av * c.x; acc[ 9] += av * c.y; acc[10] += av * c.z; acc[11] += av * c.w;
            acc[12] += av * d.x; acc[13] += av * d.y; acc[14] += av * d.z; acc[15] += av * d.w;
        }
    }
    #pragma unroll
    for (int i = 0; i < 16; ++i) m_lds[rr * 257 + j0 + i] = silu_f(acc[i]);
    __syncthreads();

    // h = mid @ Wu2 + bu2
    #pragma unroll
    for (int i = 0; i < 16; ++i) acc[i] = bu2[j0 + i];
    {
        const float* mrow = &m_lds[rr * 257];
        for (int k = 0; k < HDIM; ++k) {
            const float mv = mrow[k];
            const float4* wr = reinterpret_cast<const float4*>(Wu2 + (k << 8) + j0);
            const float4 a = wr[0], b = wr[1], c = wr[2], d = wr[3];
            acc[ 0] += mv * a.x; acc[ 1] += mv * a.y; acc[ 2] += mv * a.z; acc[ 3] += mv * a.w;
            acc[ 4] += mv * b.x; acc[ 5] += mv * b.y; acc[ 6] += mv * b.z; acc[ 7] += mv * b.w;
            acc[ 8] += mv * c.x; acc[ 9] += mv * c.y; acc[10] += mv * c.z; acc[11] += mv * c.w;
            acc[12] += mv * d.x; acc[13] += mv * d.y; acc[14] += mv * d.z; acc[15] += mv * d.w;
        }
    }
    float* hp = h_out + (r0 + rr) * HDIM + j0;
    float4* hp4 = reinterpret_cast<float4*>(hp);
    hp4[0] = make_float4(acc[0], acc[1], acc[2], acc[3]);
    hp4[1] = make_float4(acc[4], acc[5], acc[6], acc[7]);
    hp4[2] = make_float4(acc[8], acc[9], acc[10], acc[11]);
    hp4[3] = make_float4(acc[12], acc[13], acc[14], acc[15]);
}

// ---------------------------------------------------------------------------
// BN stats: column sums and sum-of-squares of h
// ---------------------------------------------------------------------------
__global__ __launch_bounds__(256) void bn_stats_kernel(
    const float* __restrict__ h, float* __restrict__ sums)
{
    const int j = threadIdx.x;
    float s = 0.0f, s2 = 0.0f;
    for (int r = blockIdx.x; r < N_NODES; r += gridDim.x) {
        const float v = h[r * HDIM + j];
        s  += v;
        s2 += v * v;
    }
    atomicAdd(&sums[j], s);
    atomicAdd(&sums[HDIM + j], s2);
}

// ---------------------------------------------------------------------------
// Final: out = x + gamma*(h-mean)*rsqrt(var+eps)+beta   (h aliases out)
// ---------------------------------------------------------------------------
__global__ __launch_bounds__(256) void final_kernel(
    const float* __restrict__ x, const float* __restrict__ sums,
    const float* __restrict__ gamma, const float* __restrict__ beta,
    float* __restrict__ out)
{
    const int i = blockIdx.x * 256 + threadIdx.x;
    const int j = i & (HDIM - 1);
    const float mean = sums[j] * (1.0f / N_NODES);
    const float var  = sums[HDIM + j] * (1.0f / N_NODES) - mean * mean;
    const float inv  = rsqrtf(var + BN_EPS);
    const float hv   = out[i];
    out[i] = x[i] + gamma[j] * (hv - mean) * inv + beta[j];
}

extern "C" void kernel_launch(void* const* d_in, const int* in_sizes, int n_in,
                              void* d_out, int out_size, void* d_ws, size_t ws_size,
                              hipStream_t stream) {
    const float* x     = (const float*)d_in[0];
    const float* rbf   = (const float*)d_in[1];
    const int*   ei    = (const int*)d_in[2];
    const float* Wf1   = (const float*)d_in[3];
    const float* bf1   = (const float*)d_in[4];
    const float* Wf2   = (const float*)d_in[5];
    const float* bf2   = (const float*)d_in[6];
    const float* Wu1   = (const float*)d_in[7];
    const float* bu1   = (const float*)d_in[8];
    const float* Wu2   = (const float*)d_in[9];
    const float* bu2   = (const float*)d_in[10];
    const float* gamma = (const float*)d_in[11];
    const float* beta  = (const float*)d_in[12];
    float* out = (float*)d_out;

    float* agg  = (float*)d_ws;                       // N*HDIM floats
    float* sums = (float*)d_ws + N_NODES * HDIM;      // 2*HDIM floats

    hipMemsetAsync(agg,  0, (size_t)N_NODES * HDIM * sizeof(float), stream);
    hipMemsetAsync(sums, 0, 2 * HDIM * sizeof(float), stream);

    edge_kernel<<<E_EDGES / EB, 256, 0, stream>>>(x, rbf, ei, Wf1, bf1, Wf2, bf2, agg);
    node_kernel<<<N_NODES / RB, 256, 0, stream>>>(agg, Wu1, bu1, Wu2, bu2, out);
    bn_stats_kernel<<<80, 256, 0, stream>>>(out, sums);
    final_kernel<<<(N_NODES * HDIM) / 256, 256, 0, stream>>>(x, sums, gamma, beta, out);
}

// Round 2
// 408.845 us; speedup vs baseline: 14.3383x; 14.3383x over previous
//
#include <hip/hip_runtime.h>
#include <hip/hip_bf16.h>

#define N_NODES 10000
#define E_EDGES 320000
#define HDIM    256
#define NG      20
#define BN_EPS  1e-5f

typedef __attribute__((ext_vector_type(8))) short short8;
typedef __attribute__((ext_vector_type(4))) float f32x4;

__device__ __forceinline__ float silu_f(float v) { return v / (1.0f + __expf(-v)); }

__device__ __forceinline__ unsigned short f2bf(float f) {
    union { float f; unsigned int u; } v; v.f = f;
    unsigned int r = v.u + 0x7fffu + ((v.u >> 16) & 1u);   // RNE
    return (unsigned short)(r >> 16);
}

// ---------------------------------------------------------------------------
// Pack W[256x256] fp32 -> bf16 MFMA fragment-linear layout:
// P[((kstep*16+ntile)*64+lane)*8+j] = W[kstep*32+(lane>>4)*8+j][ntile*16+(lane&15)]
// ---------------------------------------------------------------------------
__global__ __launch_bounds__(256) void prep_kernel(
    const float* __restrict__ Wf2, const float* __restrict__ Wu1,
    const float* __restrict__ Wu2,
    unsigned short* __restrict__ Pf2, unsigned short* __restrict__ Pu1,
    unsigned short* __restrict__ Pu2)
{
    const float* W = (blockIdx.y == 0) ? Wf2 : (blockIdx.y == 1) ? Wu1 : Wu2;
    unsigned short* P = (blockIdx.y == 0) ? Pf2 : (blockIdx.y == 1) ? Pu1 : Pu2;
    int tid   = blockIdx.x * 256 + threadIdx.x;          // 0..65535
    int j     = tid & 7;
    int lane  = (tid >> 3) & 63;
    int ntile = (tid >> 9) & 15;
    int kstep = tid >> 13;
    int k = kstep * 32 + (lane >> 4) * 8 + j;
    int n = ntile * 16 + (lane & 15);
    P[tid] = f2bf(W[k * 256 + n]);
}

// ---------------------------------------------------------------------------
// CSR build: histogram -> in-place exclusive scan -> fill (perm + nodepos)
// ---------------------------------------------------------------------------
__global__ __launch_bounds__(256) void hist_kernel(const int* __restrict__ ei_row,
                                                   int* __restrict__ cnt) {
    int e = blockIdx.x * 256 + threadIdx.x;
    atomicAdd(&cnt[ei_row[e]], 1);
}

__global__ __launch_bounds__(256) void scan_kernel(int* __restrict__ cnt) {
    __shared__ int lds[256];
    const int t = threadIdx.x;
    int carry = 0;
    for (int base = 0; base < 10240; base += 256) {
        int v = cnt[base + t];
        lds[t] = v;
        __syncthreads();
        for (int off = 1; off < 256; off <<= 1) {
            int u = (t >= off) ? lds[t - off] : 0;
            __syncthreads();
            lds[t] += u;
            __syncthreads();
        }
        cnt[base + t] = carry + lds[t] - v;   // exclusive
        carry += lds[255];
        __syncthreads();
    }
}

__global__ __launch_bounds__(256) void fill_kernel(const int* __restrict__ ei_row,
                                                   int* __restrict__ cnt,
                                                   int* __restrict__ perm,
                                                   int* __restrict__ nodepos) {
    int e = blockIdx.x * 256 + threadIdx.x;
    int r = ei_row[e];
    int pos = atomicAdd(&cnt[r], 1);
    perm[pos] = e;
    nodepos[pos] = r;
}

// ---------------------------------------------------------------------------
// Edge kernel: per block, 64 CSR-ordered edges.
//   hidden = silu(rbf@Wf1+bf1) (vector) -> LDS bf16 (swizzled)
//   filt   = hidden @ Wf2 via MFMA 16x16x32 (B from Pf2 fragment layout)
//   msg    = (filt+bf2) * x[col]  -> LDS, segmented column reduce, few atomics
// LDS map: [0,5376) rbf  [5376,5632) perm  [5632,5888) nid  [5888,6144) col
//          [6144,38912) hidA bf16 (32K)   [38912,55296) Bbuf (16K)
//          msg (32K per half) overlays hidA after the K-loop.
// ---------------------------------------------------------------------------
#define SM_RBF  0
#define SM_PERM 5376
#define SM_NID  5632
#define SM_COL  5888
#define SM_A    6144
#define SM_B    38912
#define SM_TOT  55296

__global__ __launch_bounds__(256, 2) void edge_kernel(
    const float* __restrict__ rbf, const float* __restrict__ Wf1,
    const float* __restrict__ bf1, const float* __restrict__ bf2,
    const float* __restrict__ x, const int* __restrict__ ei_col,
    const int* __restrict__ perm, const int* __restrict__ nodepos,
    const unsigned short* __restrict__ Bprep, float* __restrict__ agg)
{
    __shared__ char sm[SM_TOT];
    float* rbf_s = (float*)(sm + SM_RBF);
    int* perm_s  = (int*)(sm + SM_PERM);
    int* nid_s   = (int*)(sm + SM_NID);
    int* col_s   = (int*)(sm + SM_COL);
    unsigned short* hidA = (unsigned short*)(sm + SM_A);
    float* msgh  = (float*)(sm + SM_A);            // overlay after K-loop

    const int t  = threadIdx.x;
    const int p0 = blockIdx.x * 64;

    if (t < 64) {
        int e = perm[p0 + t];
        perm_s[t] = e;
        nid_s[t]  = nodepos[p0 + t];
        col_s[t]  = ei_col[e];
    }
    __syncthreads();

    for (int i = t; i < 64 * NG; i += 256) {
        int row = i / NG, kk = i - row * NG;
        rbf_s[row * 21 + kk] = rbf[perm_s[row] * NG + kk];
    }

    // issue B stage for ks=0 early
    const uint4* bp = (const uint4*)Bprep;
    uint4 st0 = bp[t], st1 = bp[256 + t], st2 = bp[512 + t], st3 = bp[768 + t];

    __syncthreads();

    // hidden: thread owns column k=t for all 64 rows
    {
        float w[NG];
        #pragma unroll
        for (int kk = 0; kk < NG; ++kk) w[kk] = Wf1[kk * HDIM + t];
        const float b = bf1[t];
        const int kq = t >> 3, klo = t & 7;
        for (int row = 0; row < 64; ++row) {
            float a = b;
            #pragma unroll
            for (int kk = 0; kk < NG; ++kk) a += rbf_s[row * 21 + kk] * w[kk];
            hidA[row * 256 + ((kq ^ (row & 7)) << 3) + klo] = f2bf(silu_f(a));
        }
    }

    const int l = t & 63, w = t >> 6;
    const int l15 = l & 15, l4 = l >> 4;
    const int arow = w * 16 + l15;

    f32x4 acc[16];
    #pragma unroll
    for (int n = 0; n < 16; ++n) acc[n] = (f32x4)0.0f;

    for (int ks = 0; ks < 8; ++ks) {
        __syncthreads();   // prev MFMA reads done (and hidA writes on first iter)
        {
            uint4* bb = (uint4*)(sm + SM_B);
            bb[t] = st0; bb[256 + t] = st1; bb[512 + t] = st2; bb[768 + t] = st3;
        }
        if (ks < 7) {
            int b0 = (ks + 1) * 1024;
            st0 = bp[b0 + t]; st1 = bp[b0 + 256 + t];
            st2 = bp[b0 + 512 + t]; st3 = bp[b0 + 768 + t];
        }
        __syncthreads();   // B ready
        short8 af = *(const short8*)(sm + SM_A + arow * 512 +
                                     ((((ks << 2) + l4) ^ (l & 7)) << 4));
        const short8* bbase = (const short8*)(sm + SM_B);
        #pragma unroll
        for (int n = 0; n < 16; ++n) {
            short8 bf = bbase[(n << 6) + l];
            acc[n] = __builtin_amdgcn_mfma_f32_16x16x32_bf16(af, bf, acc[n], 0, 0, 0);
        }
    }
    __syncthreads();   // all MFMA done: hidA/B regions free for msg overlay

    int posr[4];
    const float* xr[4];
    #pragma unroll
    for (int r = 0; r < 4; ++r) {
        posr[r] = w * 16 + l4 * 4 + r;
        xr[r] = x + (size_t)col_s[posr[r]] * HDIM;
    }

    // half 0: positions 0..31 (waves 0,1) ------------------------------------
    if (w < 2) {
        #pragma unroll
        for (int n = 0; n < 16; ++n) {
            int col = (n << 4) + l15;
            float bias = bf2[col];
            #pragma unroll
            for (int r = 0; r < 4; ++r) {
                float m = (acc[n][r] + bias) * xr[r][col];
                msgh[posr[r] * 256 + (col ^ ((posr[r] & 7) << 2))] = m;
            }
        }
    }
    __syncthreads();
    {
        float sum = 0.f; int cur = nid_s[0];
        for (int pos = 0; pos < 32; ++pos) {
            int nid = nid_s[pos];
            float v = msgh[pos * 256 + (t ^ ((pos & 7) << 2))];
            if (nid != cur) { atomicAdd(&agg[cur * HDIM + t], sum); sum = 0.f; cur = nid; }
            sum += v;
        }
        atomicAdd(&agg[cur * HDIM + t], sum);
    }
    __syncthreads();

    // half 1: positions 32..63 (waves 2,3) -----------------------------------
    if (w >= 2) {
        #pragma unroll
        for (int n = 0; n < 16; ++n) {
            int col = (n << 4) + l15;
            float bias = bf2[col];
            #pragma unroll
            for (int r = 0; r < 4; ++r) {
                float m = (acc[n][r] + bias) * xr[r][col];
                msgh[(posr[r] - 32) * 256 + (col ^ ((posr[r] & 7) << 2))] = m;
            }
        }
    }
    __syncthreads();
    {
        float sum = 0.f; int cur = nid_s[32];
        for (int pos = 32; pos < 64; ++pos) {
            int nid = nid_s[pos];
            float v = msgh[(pos - 32) * 256 + (t ^ ((pos & 7) << 2))];
            if (nid != cur) { atomicAdd(&agg[cur * HDIM + t], sum); sum = 0.f; cur = nid; }
            sum += v;
        }
        atomicAdd(&agg[cur * HDIM + t], sum);
    }
}

// ---------------------------------------------------------------------------
// Node kernel: h = silu(agg@Wu1+bu1)@Wu2+bu2, two fused MFMA GEMMs per tile.
// LDS: [0,32768) A bf16 swizzled, [32768,49152) Bbuf.
// ---------------------------------------------------------------------------
__global__ __launch_bounds__(256, 2) void node_kernel(
    const float* __restrict__ agg, const float* __restrict__ bu1,
    const float* __restrict__ bu2,
    const unsigned short* __restrict__ Pu1, const unsigned short* __restrict__ Pu2,
    float* __restrict__ hout)
{
    __shared__ char sm[49152];
    unsigned short* A = (unsigned short*)sm;

    const int t  = threadIdx.x;
    const int r0 = blockIdx.x * 64;

    // stage A tile from agg (fp32 -> bf16, swizzled); thread owns col t
    {
        const int kq = t >> 3, klo = t & 7;
        for (int row = 0; row < 64; ++row) {
            int gr = r0 + row;
            float v = (gr < N_NODES) ? agg[gr * HDIM + t] : 0.f;
            A[row * 256 + ((kq ^ (row & 7)) << 3) + klo] = f2bf(v);
        }
    }

    const int l = t & 63, w = t >> 6;
    const int l15 = l & 15, l4 = l >> 4;
    const int arow = w * 16 + l15;

    const uint4* bp = (const uint4*)Pu1;
    uint4 st0 = bp[t], st1 = bp[256 + t], st2 = bp[512 + t], st3 = bp[768 + t];

    f32x4 acc[16];
    #pragma unroll
    for (int n = 0; n < 16; ++n) acc[n] = (f32x4)0.0f;

    for (int ks = 0; ks < 8; ++ks) {
        __syncthreads();
        {
            uint4* bb = (uint4*)(sm + 32768);
            bb[t] = st0; bb[256 + t] = st1; bb[512 + t] = st2; bb[768 + t] = st3;
        }
        if (ks < 7) {
            int b0 = (ks + 1) * 1024;
            st0 = bp[b0 + t]; st1 = bp[b0 + 256 + t];
            st2 = bp[b0 + 512 + t]; st3 = bp[b0 + 768 + t];
        }
        __syncthreads();
        short8 af = *(const short8*)(sm + arow * 512 +
                                     ((((ks << 2) + l4) ^ (l & 7)) << 4));
        const short8* bbase = (const short8*)(sm + 32768);
        #pragma unroll
        for (int n = 0; n < 16; ++n) {
            short8 bf = bbase[(n << 6) + l];
            acc[n] = __builtin_amdgcn_mfma_f32_16x16x32_bf16(af, bf, acc[n], 0, 0, 0);
        }
    }
    __syncthreads();   // GEMM1 done; A free

    // mid = silu(acc + bu1) -> A (bf16, swizzled) ; prefetch Pu2 ks=0
    const uint4* bp2 = (const uint4*)Pu2;
    st0 = bp2[t]; st1 = bp2[256 + t]; st2 = bp2[512 + t]; st3 = bp2[768 + t];
    #pragma unroll
    for (int n = 0; n < 16; ++n) {
        int col = (n << 4) + l15;
        float bias = bu1[col];
        #pragma unroll
        for (int r = 0; r < 4; ++r) {
            int pos = w * 16 + l4 * 4 + r;
            float m = silu_f(acc[n][r] + bias);
            A[pos * 256 + (((col >> 3) ^ (pos & 7)) << 3) + (col & 7)] = f2bf(m);
        }
        acc[n] = (f32x4)0.0f;
    }

    for (int ks = 0; ks < 8; ++ks) {
        __syncthreads();
        {
            uint4* bb = (uint4*)(sm + 32768);
            bb[t] = st0; bb[256 + t] = st1; bb[512 + t] = st2; bb[768 + t] = st3;
        }
        if (ks < 7) {
            int b0 = (ks + 1) * 1024;
            st0 = bp2[b0 + t]; st1 = bp2[b0 + 256 + t];
            st2 = bp2[b0 + 512 + t]; st3 = bp2[b0 + 768 + t];
        }
        __syncthreads();
        short8 af = *(const short8*)(sm + arow * 512 +
                                     ((((ks << 2) + l4) ^ (l & 7)) << 4));
        const short8* bbase = (const short8*)(sm + 32768);
        #pragma unroll
        for (int n = 0; n < 16; ++n) {
            short8 bf = bbase[(n << 6) + l];
            acc[n] = __builtin_amdgcn_mfma_f32_16x16x32_bf16(af, bf, acc[n], 0, 0, 0);
        }
    }

    #pragma unroll
    for (int n = 0; n < 16; ++n) {
        int col = (n << 4) + l15;
        float bias = bu2[col];
        #pragma unroll
        for (int r = 0; r < 4; ++r) {
            int pos = w * 16 + l4 * 4 + r;
            int gr = r0 + pos;
            if (gr < N_NODES) hout[gr * HDIM + col] = acc[n][r] + bias;
        }
    }
}

// ---------------------------------------------------------------------------
__global__ __launch_bounds__(256) void bn_stats_kernel(
    const float* __restrict__ h, float* __restrict__ sums)
{
    const int j = threadIdx.x;
    float s = 0.f, s2 = 0.f;
    for (int r = blockIdx.x; r < N_NODES; r += gridDim.x) {
        float v = h[r * HDIM + j];
        s += v; s2 += v * v;
    }
    atomicAdd(&sums[j], s);
    atomicAdd(&sums[HDIM + j], s2);
}

__global__ __launch_bounds__(256) void final_kernel(
    const float* __restrict__ x, const float* __restrict__ sums,
    const float* __restrict__ gamma, const float* __restrict__ beta,
    float* __restrict__ out)
{
    const int i = blockIdx.x * 256 + threadIdx.x;
    const int j = i & (HDIM - 1);
    const float mean = sums[j] * (1.0f / N_NODES);
    const float var  = sums[HDIM + j] * (1.0f / N_NODES) - mean * mean;
    const float inv  = rsqrtf(var + BN_EPS);
    const float hv   = out[i];
    out[i] = x[i] + gamma[j] * (hv - mean) * inv + beta[j];
}

extern "C" void kernel_launch(void* const* d_in, const int* in_sizes, int n_in,
                              void* d_out, int out_size, void* d_ws, size_t ws_size,
                              hipStream_t stream) {
    const float* x     = (const float*)d_in[0];
    const float* rbf   = (const float*)d_in[1];
    const int*   ei    = (const int*)d_in[2];
    const float* Wf1   = (const float*)d_in[3];
    const float* bf1   = (const float*)d_in[4];
    const float* Wf2   = (const float*)d_in[5];
    const float* bf2   = (const float*)d_in[6];
    const float* Wu1   = (const float*)d_in[7];
    const float* bu1   = (const float*)d_in[8];
    const float* Wu2   = (const float*)d_in[9];
    const float* bu2   = (const float*)d_in[10];
    const float* gamma = (const float*)d_in[11];
    const float* beta  = (const float*)d_in[12];
    float* out = (float*)d_out;

    char* ws = (char*)d_ws;
    float* agg     = (float*)(ws);                     // 10,240,000 B
    float* sums    = (float*)(ws + 10240000);          // 2,048 B
    int*   cnt     = (int*)(ws + 10242048);            // 40,960 B
    int*   perm    = (int*)(ws + 10283008);            // 1,280,000 B
    int*   nodepos = (int*)(ws + 11563008);            // 1,280,000 B
    unsigned short* Pf2 = (unsigned short*)(ws + 12843008);   // 131,072 B
    unsigned short* Pu1 = (unsigned short*)(ws + 12974080);   // 131,072 B
    unsigned short* Pu2 = (unsigned short*)(ws + 13105152);   // 131,072 B

    hipMemsetAsync(agg,  0, 10240000, stream);
    hipMemsetAsync(sums, 0, 2048, stream);
    hipMemsetAsync(cnt,  0, 40960, stream);

    prep_kernel<<<dim3(256, 3), 256, 0, stream>>>(Wf2, Wu1, Wu2, Pf2, Pu1, Pu2);
    hist_kernel<<<E_EDGES / 256, 256, 0, stream>>>(ei, cnt);
    scan_kernel<<<1, 256, 0, stream>>>(cnt);
    fill_kernel<<<E_EDGES / 256, 256, 0, stream>>>(ei, cnt, perm, nodepos);

    edge_kernel<<<E_EDGES / 64, 256, 0, stream>>>(
        rbf, Wf1, bf1, bf2, x, ei + E_EDGES, perm, nodepos, Pf2, agg);
    node_kernel<<<(N_NODES + 63) / 64, 256, 0, stream>>>(
        agg, bu1, bu2, Pu1, Pu2, out);
    bn_stats_kernel<<<256, 256, 0, stream>>>(out, sums);
    final_kernel<<<(N_NODES * HDIM) / 256, 256, 0, stream>>>(x, sums, gamma, beta, out);
}

// Round 3
// 219.707 us; speedup vs baseline: 26.6817x; 1.8609x over previous
//
#include <hip/hip_runtime.h>

#define N_NODES 10000
#define E_EDGES 320000
#define HDIM    256
#define NG      20
#define BN_EPS  1e-5f

typedef __attribute__((ext_vector_type(8))) short short8;
typedef __attribute__((ext_vector_type(4))) float f32x4;

__device__ __forceinline__ float silu_f(float v) { return v / (1.0f + __expf(-v)); }

__device__ __forceinline__ unsigned short f2bf(float f) {
    union { float f; unsigned int u; } v; v.f = f;
    unsigned int r = v.u + 0x7fffu + ((v.u >> 16) & 1u);   // RNE
    return (unsigned short)(r >> 16);
}

// ---------------------------------------------------------------------------
// Pack W[256x256] fp32 -> bf16 MFMA fragment layout:
// P[((kstep*16+ntile)*64+lane)*8+j] = W[kstep*32+(lane>>4)*8+j][ntile*16+(lane&15)]
// ---------------------------------------------------------------------------
__global__ __launch_bounds__(256) void prep_kernel(
    const float* __restrict__ Wf2, const float* __restrict__ Wu1,
    const float* __restrict__ Wu2,
    unsigned short* __restrict__ Pf2, unsigned short* __restrict__ Pu1,
    unsigned short* __restrict__ Pu2)
{
    const float* W = (blockIdx.y == 0) ? Wf2 : (blockIdx.y == 1) ? Wu1 : Wu2;
    unsigned short* P = (blockIdx.y == 0) ? Pf2 : (blockIdx.y == 1) ? Pu1 : Pu2;
    int tid   = blockIdx.x * 256 + threadIdx.x;          // 0..65535
    int j     = tid & 7;
    int lane  = (tid >> 3) & 63;
    int ntile = (tid >> 9) & 15;
    int kstep = tid >> 13;
    int k = kstep * 32 + (lane >> 4) * 8 + j;
    int n = ntile * 16 + (lane & 15);
    P[tid] = f2bf(W[k * 256 + n]);
}

// Pack Wf1[20x256] (+bf1 as k=20 row, zeros 21..31) -> one K=32 fragment slab
__global__ __launch_bounds__(256) void prep1_kernel(
    const float* __restrict__ Wf1, const float* __restrict__ bf1,
    unsigned short* __restrict__ P1)
{
    int tid = blockIdx.x * 256 + threadIdx.x;            // 0..8191
    int j     = tid & 7;
    int lane  = (tid >> 3) & 63;
    int ntile = tid >> 9;
    int k = (lane >> 4) * 8 + j;
    int n = ntile * 16 + (lane & 15);
    float v = (k < NG) ? Wf1[k * 256 + n] : (k == NG ? bf1[n] : 0.0f);
    P1[tid] = f2bf(v);
}

// ---------------------------------------------------------------------------
// CSR build
// ---------------------------------------------------------------------------
__global__ __launch_bounds__(256) void hist_kernel(const int* __restrict__ ei_row,
                                                   int* __restrict__ cnt) {
    int e = blockIdx.x * 256 + threadIdx.x;
    atomicAdd(&cnt[ei_row[e]], 1);
}

// 10240 counters; thread t owns 40 contiguous; block scan of totals
__global__ __launch_bounds__(256) void scan_kernel(int* __restrict__ cnt) {
    __shared__ int tot[256];
    const int t = threadIdx.x;
    int loc[40];
    int s = 0;
    #pragma unroll
    for (int i = 0; i < 40; ++i) { loc[i] = cnt[t * 40 + i]; s += loc[i]; }
    tot[t] = s;
    __syncthreads();
    for (int off = 1; off < 256; off <<= 1) {
        int u = (t >= off) ? tot[t - off] : 0;
        __syncthreads();
        tot[t] += u;
        __syncthreads();
    }
    int pre = tot[t] - s;   // exclusive prefix of this chunk
    #pragma unroll
    for (int i = 0; i < 40; ++i) { int v = loc[i]; cnt[t * 40 + i] = pre; pre += v; }
}

__global__ __launch_bounds__(256) void fill_kernel(const int* __restrict__ ei_row,
                                                   int* __restrict__ cnt,
                                                   int* __restrict__ perm,
                                                   int* __restrict__ nodepos) {
    int e = blockIdx.x * 256 + threadIdx.x;
    int r = ei_row[e];
    int pos = atomicAdd(&cnt[r], 1);
    perm[pos] = e;
    nodepos[pos] = r;
}

// ---------------------------------------------------------------------------
// Edge kernel: 64 CSR-ordered edges / block, 4 waves, wave owns 4 n-tiles.
//   GEMM1 (MFMA, K=32 w/ bias row): hidden = silu(rbf@Wf1+bf1) -> LDS bf16 swz
//   GEMM2 (MFMA, barrier-free, B direct from L2): filt = hidden@Wf2
//   msg = (filt+bf2)*x[col] -> f32 LDS (2 half passes), serial segment reduce,
//   few atomics into agg.
// ---------------------------------------------------------------------------
#define SM_A1  0        // [64][40] bf16, 80B rows           (5120 B)
#define SM_NID 5120     // 64 int
#define SM_COL 5376     // 64 int
#define SM_HID 5632     // 32768 B: hid bf16 [64][256] swz / msg f32 [32][256] swz
#define SM_TOT 38400

__global__ __launch_bounds__(256, 3) void edge_kernel(
    const float* __restrict__ rbf, const int* __restrict__ ei_col,
    const int* __restrict__ perm, const int* __restrict__ nodepos,
    const unsigned short* __restrict__ P1, const unsigned short* __restrict__ P2,
    const float* __restrict__ bf2, const float* __restrict__ x,
    float* __restrict__ agg)
{
    __shared__ char sm[SM_TOT];
    unsigned short* A1 = (unsigned short*)(sm + SM_A1);
    int* nid_s = (int*)(sm + SM_NID);
    int* col_s = (int*)(sm + SM_COL);

    const int t  = threadIdx.x;
    const int p0 = blockIdx.x * 64;
    const int l = t & 63, w = t >> 6;
    const int l15 = l & 15, l4 = l >> 4;

    if (t < 64) {
        nid_s[t] = nodepos[p0 + t];
        col_s[t] = ei_col[perm[p0 + t]];
    }
    // stage rbf -> A1 bf16 (K rows 80B); k=20 -> 1.0 (bias row), 21..31 -> 0
    {
        const int row = t >> 2, q = t & 3;
        const int e = perm[p0 + row];
        const float* rp = rbf + (size_t)e * NG + q * 5;
        #pragma unroll
        for (int i = 0; i < 5; ++i) A1[row * 40 + q * 5 + i] = f2bf(rp[i]);
        if (q == 3) {
            A1[row * 40 + 20] = 0x3F80;   // 1.0 bf16
            #pragma unroll
            for (int k = 21; k < 32; ++k) A1[row * 40 + k] = 0;
        }
    }

    // GEMM1 B fragments (issue loads before barrier)
    short8 b1[4];
    #pragma unroll
    for (int n = 0; n < 4; ++n)
        b1[n] = *(const short8*)(P1 + ((4 * w + n) * 64 + l) * 8);

    __syncthreads();

    f32x4 acc[4][4];   // [n][m]
    #pragma unroll
    for (int n = 0; n < 4; ++n)
        #pragma unroll
        for (int m = 0; m < 4; ++m) acc[n][m] = (f32x4)0.0f;

    // GEMM1: one K=32 step
    #pragma unroll
    for (int m = 0; m < 4; ++m) {
        short8 af = *(const short8*)(sm + SM_A1 + (m * 16 + l15) * 80 + l4 * 16);
        #pragma unroll
        for (int n = 0; n < 4; ++n)
            acc[n][m] = __builtin_amdgcn_mfma_f32_16x16x32_bf16(af, b1[n], acc[n][m], 0, 0, 0);
    }

    // silu -> hidA (bf16, chunk-XOR swizzled)
    #pragma unroll
    for (int n = 0; n < 4; ++n) {
        const int col = w * 64 + n * 16 + l15;
        #pragma unroll
        for (int m = 0; m < 4; ++m)
            #pragma unroll
            for (int r = 0; r < 4; ++r) {
                int row = m * 16 + l4 * 4 + r;
                *(unsigned short*)(sm + SM_HID + row * 512 +
                    ((((col >> 3) ^ (row & 7))) << 4) + (col & 7) * 2) =
                    f2bf(silu_f(acc[n][m][r]));
            }
    }
    __syncthreads();

    // GEMM2: barrier-free; B fragments straight from L2 (wave owns n-tiles 4w..4w+3)
    #pragma unroll
    for (int n = 0; n < 4; ++n)
        #pragma unroll
        for (int m = 0; m < 4; ++m) acc[n][m] = (f32x4)0.0f;

    short8 bcur[4];
    #pragma unroll
    for (int n = 0; n < 4; ++n)
        bcur[n] = *(const short8*)(P2 + (((0 * 16 + 4 * w + n) * 64) + l) * 8);

    for (int ks = 0; ks < 8; ++ks) {
        short8 bnext[4];
        if (ks < 7) {
            #pragma unroll
            for (int n = 0; n < 4; ++n)
                bnext[n] = *(const short8*)(P2 + ((((ks + 1) * 16 + 4 * w + n) * 64) + l) * 8);
        }
        #pragma unroll
        for (int m = 0; m < 4; ++m) {
            const int row = m * 16 + l15;
            short8 af = *(const short8*)(sm + SM_HID + row * 512 +
                           ((((ks << 2) + l4) ^ (row & 7)) << 4));
            #pragma unroll
            for (int n = 0; n < 4; ++n)
                acc[n][m] = __builtin_amdgcn_mfma_f32_16x16x32_bf16(af, bcur[n], acc[n][m], 0, 0, 0);
        }
        if (ks < 7) {
            #pragma unroll
            for (int n = 0; n < 4; ++n) bcur[n] = bnext[n];
        }
    }
    __syncthreads();   // hidA region free -> msg overlay

    float bc[4];
    #pragma unroll
    for (int n = 0; n < 4; ++n) bc[n] = bf2[w * 64 + n * 16 + l15];

    float sum = 0.0f;
    int cur = nid_s[0];
    float* msgf = (float*)(sm + SM_HID);

    #pragma unroll
    for (int ms = 0; ms < 2; ++ms) {
        // write half: rows ms*32 .. ms*32+31
        #pragma unroll
        for (int mm = 0; mm < 2; ++mm) {
            const int m = ms * 2 + mm;
            #pragma unroll
            for (int r = 0; r < 4; ++r) {
                const int row = m * 16 + l4 * 4 + r;
                const int pos = row & 31;
                const float* xp = x + (size_t)col_s[row] * HDIM;
                #pragma unroll
                for (int n = 0; n < 4; ++n) {
                    const int col = w * 64 + n * 16 + l15;
                    float mv = (acc[n][m][r] + bc[n]) * xp[col];
                    *(float*)(sm + SM_HID + pos * 1024 +
                        ((((col >> 2) ^ (pos & 7))) << 4) + (col & 3) * 4) = mv;
                }
            }
        }
        __syncthreads();
        // reduce half: thread t owns column t; segment flush on nid change
        for (int pos = 0; pos < 32; ++pos) {
            const int row = ms * 32 + pos;
            const int nid = nid_s[row];
            float v = *(const float*)(sm + SM_HID + pos * 1024 +
                        ((((t >> 2) ^ (pos & 7))) << 4) + (t & 3) * 4);
            if (nid != cur) {
                atomicAdd(&agg[(size_t)cur * HDIM + t], sum);
                sum = 0.0f; cur = nid;
            }
            sum += v;
        }
        __syncthreads();
    }
    atomicAdd(&agg[(size_t)cur * HDIM + t], sum);
}

// ---------------------------------------------------------------------------
// Node kernel: h = silu(agg@Wu1+bu1)@Wu2+bu2 ; fused BN partial sums.
// Barrier-free GEMM loops, B direct from L2.
// ---------------------------------------------------------------------------
__global__ __launch_bounds__(256, 3) void node_kernel(
    const float* __restrict__ agg, const float* __restrict__ bu1,
    const float* __restrict__ bu2,
    const unsigned short* __restrict__ Pu1, const unsigned short* __restrict__ Pu2,
    float* __restrict__ hout, float* __restrict__ sums)
{
    __shared__ unsigned short A[64 * 256];   // 32KB, chunk-XOR swizzled
    const int t  = threadIdx.x;
    const int r0 = blockIdx.x * 64;
    const int l = t & 63, w = t >> 6;
    const int l15 = l & 15, l4 = l >> 4;

    {   // stage A: thread t owns column t
        const int kq = t >> 3, klo = t & 7;
        for (int row = 0; row < 64; ++row) {
            int gr = r0 + row;
            float v = (gr < N_NODES) ? agg[(size_t)gr * HDIM + t] : 0.0f;
            A[row * 256 + ((kq ^ (row & 7)) << 3) + klo] = f2bf(v);
        }
    }
    __syncthreads();

    f32x4 acc[4][4];
    #pragma unroll
    for (int n = 0; n < 4; ++n)
        #pragma unroll
        for (int m = 0; m < 4; ++m) acc[n][m] = (f32x4)0.0f;

    short8 bcur[4];
    #pragma unroll
    for (int n = 0; n < 4; ++n)
        bcur[n] = *(const short8*)(Pu1 + (((4 * w + n) * 64) + l) * 8);

    for (int ks = 0; ks < 8; ++ks) {
        short8 bnext[4];
        if (ks < 7) {
            #pragma unroll
            for (int n = 0; n < 4; ++n)
                bnext[n] = *(const short8*)(Pu1 + ((((ks + 1) * 16 + 4 * w + n) * 64) + l) * 8);
        }
        #pragma unroll
        for (int m = 0; m < 4; ++m) {
            const int row = m * 16 + l15;
            short8 af = *(const short8*)((char*)A + row * 512 +
                           ((((ks << 2) + l4) ^ (row & 7)) << 4));
            #pragma unroll
            for (int n = 0; n < 4; ++n)
                acc[n][m] = __builtin_amdgcn_mfma_f32_16x16x32_bf16(af, bcur[n], acc[n][m], 0, 0, 0);
        }
        if (ks < 7) {
            #pragma unroll
            for (int n = 0; n < 4; ++n) bcur[n] = bnext[n];
        }
    }
    __syncthreads();   // all A reads done

    // mid = silu(acc + bu1) -> A (same layout)
    #pragma unroll
    for (int n = 0; n < 4; ++n) {
        const int col = w * 64 + n * 16 + l15;
        const float b = bu1[col];
        #pragma unroll
        for (int m = 0; m < 4; ++m)
            #pragma unroll
            for (int r = 0; r < 4; ++r) {
                int row = m * 16 + l4 * 4 + r;
                A[row * 256 + (((col >> 3) ^ (row & 7)) << 3) + (col & 7)] =
                    f2bf(silu_f(acc[n][m][r] + b));
            }
    }
    #pragma unroll
    for (int n = 0; n < 4; ++n)
        #pragma unroll
        for (int m = 0; m < 4; ++m) acc[n][m] = (f32x4)0.0f;
    __syncthreads();

    #pragma unroll
    for (int n = 0; n < 4; ++n)
        bcur[n] = *(const short8*)(Pu2 + (((4 * w + n) * 64) + l) * 8);

    for (int ks = 0; ks < 8; ++ks) {
        short8 bnext[4];
        if (ks < 7) {
            #pragma unroll
            for (int n = 0; n < 4; ++n)
                bnext[n] = *(const short8*)(Pu2 + ((((ks + 1) * 16 + 4 * w + n) * 64) + l) * 8);
        }
        #pragma unroll
        for (int m = 0; m < 4; ++m) {
            const int row = m * 16 + l15;
            short8 af = *(const short8*)((char*)A + row * 512 +
                           ((((ks << 2) + l4) ^ (row & 7)) << 4));
            #pragma unroll
            for (int n = 0; n < 4; ++n)
                acc[n][m] = __builtin_amdgcn_mfma_f32_16x16x32_bf16(af, bcur[n], acc[n][m], 0, 0, 0);
        }
        if (ks < 7) {
            #pragma unroll
            for (int n = 0; n < 4; ++n) bcur[n] = bnext[n];
        }
    }

    // epilogue: h write + BN partials (cross-l4 shuffle reduce, atomics)
    #pragma unroll
    for (int n = 0; n < 4; ++n) {
        const int col = w * 64 + n * 16 + l15;
        const float b = bu2[col];
        float s = 0.0f, s2 = 0.0f;
        #pragma unroll
        for (int m = 0; m < 4; ++m)
            #pragma unroll
            for (int r = 0; r < 4; ++r) {
                int gr = r0 + m * 16 + l4 * 4 + r;
                float h = acc[n][m][r] + b;
                if (gr < N_NODES) {
                    hout[(size_t)gr * HDIM + col] = h;
                    s += h; s2 += h * h;
                }
            }
        s  += __shfl_xor(s, 16);  s  += __shfl_xor(s, 32);
        s2 += __shfl_xor(s2, 16); s2 += __shfl_xor(s2, 32);
        if (l4 == 0) {
            atomicAdd(&sums[col], s);
            atomicAdd(&sums[HDIM + col], s2);
        }
    }
}

// ---------------------------------------------------------------------------
__global__ __launch_bounds__(256) void final_kernel(
    const float* __restrict__ x, const float* __restrict__ sums,
    const float* __restrict__ gamma, const float* __restrict__ beta,
    float* __restrict__ out)
{
    const int i = blockIdx.x * 256 + threadIdx.x;
    const int j = i & (HDIM - 1);
    const float mean = sums[j] * (1.0f / N_NODES);
    const float var  = sums[HDIM + j] * (1.0f / N_NODES) - mean * mean;
    const float inv  = rsqrtf(var + BN_EPS);
    const float hv   = out[i];
    out[i] = x[i] + gamma[j] * (hv - mean) * inv + beta[j];
}

extern "C" void kernel_launch(void* const* d_in, const int* in_sizes, int n_in,
                              void* d_out, int out_size, void* d_ws, size_t ws_size,
                              hipStream_t stream) {
    const float* x     = (const float*)d_in[0];
    const float* rbf   = (const float*)d_in[1];
    const int*   ei    = (const int*)d_in[2];
    const float* Wf1   = (const float*)d_in[3];
    const float* bf1   = (const float*)d_in[4];
    const float* Wf2   = (const float*)d_in[5];
    const float* bf2   = (const float*)d_in[6];
    const float* Wu1   = (const float*)d_in[7];
    const float* bu1   = (const float*)d_in[8];
    const float* Wu2   = (const float*)d_in[9];
    const float* bu2   = (const float*)d_in[10];
    const float* gamma = (const float*)d_in[11];
    const float* beta  = (const float*)d_in[12];
    float* out = (float*)d_out;

    char* ws = (char*)d_ws;
    float* agg     = (float*)(ws);                            // 10,240,000 B
    float* sums    = (float*)(ws + 10240000);                 // 2,048 B
    int*   cnt     = (int*)(ws + 10242048);                   // 40,960 B
    int*   perm    = (int*)(ws + 10283008);                   // 1,280,000 B
    int*   nodepos = (int*)(ws + 11563008);                   // 1,280,000 B
    unsigned short* Pf2 = (unsigned short*)(ws + 12843008);   // 131,072 B
    unsigned short* Pu1 = (unsigned short*)(ws + 12974080);   // 131,072 B
    unsigned short* Pu2 = (unsigned short*)(ws + 13105152);   // 131,072 B
    unsigned short* P1  = (unsigned short*)(ws + 13236224);   // 16,384 B

    hipMemsetAsync(agg,  0, 10240000, stream);
    hipMemsetAsync(sums, 0, 2048, stream);
    hipMemsetAsync(cnt,  0, 40960, stream);

    prep_kernel<<<dim3(256, 3), 256, 0, stream>>>(Wf2, Wu1, Wu2, Pf2, Pu1, Pu2);
    prep1_kernel<<<32, 256, 0, stream>>>(Wf1, bf1, P1);
    hist_kernel<<<E_EDGES / 256, 256, 0, stream>>>(ei, cnt);
    scan_kernel<<<1, 256, 0, stream>>>(cnt);
    fill_kernel<<<E_EDGES / 256, 256, 0, stream>>>(ei, cnt, perm, nodepos);

    edge_kernel<<<E_EDGES / 64, 256, 0, stream>>>(
        rbf, ei + E_EDGES, perm, nodepos, P1, Pf2, bf2, x, agg);
    node_kernel<<<(N_NODES + 63) / 64, 256, 0, stream>>>(
        agg, bu1, bu2, Pu1, Pu2, out, sums);
    final_kernel<<<(N_NODES * HDIM) / 256, 256, 0, stream>>>(x, sums, gamma, beta, out);
}

// Round 4
// 205.488 us; speedup vs baseline: 28.5280x; 1.0692x over previous
//
#include <hip/hip_runtime.h>

#define N_NODES 10000
#define E_EDGES 320000
#define HDIM    256
#define NG      20
#define BN_EPS  1e-5f

typedef __attribute__((ext_vector_type(8))) short short8;
typedef __attribute__((ext_vector_type(4))) float f32x4;

__device__ __forceinline__ float silu_f(float v) {
    // v * rcp(1+exp(-v)): ~5 VALU instrs, ~1ulp (bf16-rounded anyway)
    float e = __expf(-v);
    return v * __builtin_amdgcn_rcpf(1.0f + e);
}

__device__ __forceinline__ unsigned int cvt_pk(float lo, float hi) {
    unsigned int r;
    asm("v_cvt_pk_bf16_f32 %0, %1, %2" : "=v"(r) : "v"(lo), "v"(hi));
    return r;
}

__device__ __forceinline__ unsigned short f2bf(float f) {
    union { float f; unsigned int u; } v; v.f = f;
    unsigned int r = v.u + 0x7fffu + ((v.u >> 16) & 1u);   // RNE
    return (unsigned short)(r >> 16);
}

// ---------------------------------------------------------------------------
// Pack W[256x256] fp32 -> bf16 MFMA fragment layout (serves as A-frag of Wᵀ
// or B-frag of W -- same lane layout):
// P[((kstep*16+tile)*64+lane)*8+j] = W[kstep*32+(lane>>4)*8+j][tile*16+(lane&15)]
// y==3: Wf1[20x256]+bf1 (k=20 bias row, zeros 21..31) -> one K=32 slab.
// ---------------------------------------------------------------------------
__global__ __launch_bounds__(256) void prep_kernel(
    const float* __restrict__ Wf2, const float* __restrict__ Wu1,
    const float* __restrict__ Wu2, const float* __restrict__ Wf1,
    const float* __restrict__ bf1,
    unsigned short* __restrict__ Pf2, unsigned short* __restrict__ Pu1,
    unsigned short* __restrict__ Pu2, unsigned short* __restrict__ P1)
{
    if (blockIdx.y == 3) {
        if (blockIdx.x >= 32) return;
        int tid = blockIdx.x * 256 + threadIdx.x;         // 0..8191
        int j     = tid & 7;
        int lane  = (tid >> 3) & 63;
        int ntile = tid >> 9;
        int k = (lane >> 4) * 8 + j;
        int n = ntile * 16 + (lane & 15);
        float v = (k < NG) ? Wf1[k * 256 + n] : (k == NG ? bf1[n] : 0.0f);
        P1[tid] = f2bf(v);
        return;
    }
    const float* W = (blockIdx.y == 0) ? Wf2 : (blockIdx.y == 1) ? Wu1 : Wu2;
    unsigned short* P = (blockIdx.y == 0) ? Pf2 : (blockIdx.y == 1) ? Pu1 : Pu2;
    int tid   = blockIdx.x * 256 + threadIdx.x;           // 0..65535
    int j     = tid & 7;
    int lane  = (tid >> 3) & 63;
    int ntile = (tid >> 9) & 15;
    int kstep = tid >> 13;
    int k = kstep * 32 + (lane >> 4) * 8 + j;
    int n = ntile * 16 + (lane & 15);
    P[tid] = f2bf(W[k * 256 + n]);
}

// ---------------------------------------------------------------------------
// CSR build
// ---------------------------------------------------------------------------
__global__ __launch_bounds__(256) void hist_kernel(const int* __restrict__ ei_row,
                                                   int* __restrict__ cnt) {
    int e = blockIdx.x * 256 + threadIdx.x;
    atomicAdd(&cnt[ei_row[e]], 1);
}

__global__ __launch_bounds__(256) void scan_kernel(int* __restrict__ cnt) {
    __shared__ int tot[256];
    const int t = threadIdx.x;
    int loc[40];
    int s = 0;
    #pragma unroll
    for (int i = 0; i < 40; ++i) { loc[i] = cnt[t * 40 + i]; s += loc[i]; }
    tot[t] = s;
    __syncthreads();
    for (int off = 1; off < 256; off <<= 1) {
        int u = (t >= off) ? tot[t - off] : 0;
        __syncthreads();
        tot[t] += u;
        __syncthreads();
    }
    int pre = tot[t] - s;
    #pragma unroll
    for (int i = 0; i < 40; ++i) { int v = loc[i]; cnt[t * 40 + i] = pre; pre += v; }
}

__global__ __launch_bounds__(256) void fill_kernel(const int* __restrict__ ei_row,
                                                   int* __restrict__ cnt,
                                                   int* __restrict__ perm,
                                                   int* __restrict__ nodepos) {
    int e = blockIdx.x * 256 + threadIdx.x;
    int r = ei_row[e];
    int pos = atomicAdd(&cnt[r], 1);
    perm[pos] = e;
    nodepos[pos] = r;
}

// ---------------------------------------------------------------------------
// Edge kernel: 64 CSR-ordered edges / block, 4 waves.
// GEMM1 (swapped): hiddenᵀ = Wf1ᵀ·rbfᵀ  -> thread holds 4 consecutive hidcols
//   -> silu + cvt_pk + b64 stores to hid[edge][k] (XOR-swizzled).
// GEMM2 (swapped): filtᵀ = Wf2ᵀ·hiddenᵀ -> thread holds 4 consecutive filtcols
//   -> float4 x gather, float4 bias, b128 msg writes; serial segment reduce.
// ---------------------------------------------------------------------------
#define SM_NID 0
#define SM_COL 256
#define SM_RBF 512      // [64][32] bf16 rows of 64 B        (4096 B)
#define SM_HID 4608     // 32768 B: hid bf16 [64][256] swz / msg f32 [32][256] swz
#define SM_TOT 37376

__global__ __launch_bounds__(256, 3) void edge_kernel(
    const float* __restrict__ rbf, const int* __restrict__ ei_col,
    const int* __restrict__ perm, const int* __restrict__ nodepos,
    const unsigned short* __restrict__ P1, const unsigned short* __restrict__ P2,
    const float* __restrict__ bf2, const float* __restrict__ x,
    float* __restrict__ agg)
{
    __shared__ char sm[SM_TOT];
    int* nid_s = (int*)(sm + SM_NID);
    int* col_s = (int*)(sm + SM_COL);

    const int t = threadIdx.x;
    int blk = blockIdx.x;
    blk = (blk & 7) * (E_EDGES / 64 / 8) + (blk >> 3);   // XCD swizzle (5000%8==0)
    const int p0 = blk * 64;
    const int l = t & 63, w = t >> 6;
    const int l15 = l & 15, l4 = l >> 4;

    if (t < 64) {
        nid_s[t] = nodepos[p0 + t];
        col_s[t] = ei_col[perm[p0 + t]];
    }
    // rbf -> LDS bf16 [64][32]; k=20 bias row (1.0), 21..31 zero
    if (t < 128) {
        const int row = t >> 1, half = t & 1;
        const float* rp = rbf + (size_t)perm[p0 + row] * NG + half * 10;
        float v[10];
        if (half == 0) {
            float4 a = *(const float4*)rp, b = *(const float4*)(rp + 4);
            float2 c = *(const float2*)(rp + 8);
            v[0]=a.x; v[1]=a.y; v[2]=a.z; v[3]=a.w; v[4]=b.x;
            v[5]=b.y; v[6]=b.z; v[7]=b.w; v[8]=c.x; v[9]=c.y;
        } else {
            float2 a = *(const float2*)rp;
            float4 b = *(const float4*)(rp + 2), c = *(const float4*)(rp + 6);
            v[0]=a.x; v[1]=a.y; v[2]=b.x; v[3]=b.y; v[4]=b.z;
            v[5]=b.w; v[6]=c.x; v[7]=c.y; v[8]=c.z; v[9]=c.w;
        }
        unsigned int* dst = (unsigned int*)(sm + SM_RBF + row * 64 + half * 20);
        #pragma unroll
        for (int i = 0; i < 5; ++i) dst[i] = cvt_pk(v[2*i], v[2*i+1]);
    } else if (t < 192) {
        const int row = t - 128;
        *(unsigned long long*)(sm + SM_RBF + row * 64 + 40) = 0x3F80ull; // 1.0,0,0,0
        *(uint4*)(sm + SM_RBF + row * 64 + 48) = make_uint4(0, 0, 0, 0);
    }

    // GEMM1 A-frags (Wf1ᵀ) and GEMM2 ks=0 A-frags (Wf2ᵀ) from global
    short8 a1[4], acur[4];
    #pragma unroll
    for (int mt = 0; mt < 4; ++mt) {
        a1[mt]   = *(const short8*)(P1 + ((4 * w + mt) * 64 + l) * 8);
        acur[mt] = *(const short8*)(P2 + ((4 * w + mt) * 64 + l) * 8);
    }

    __syncthreads();

    f32x4 acc[4][4];   // [mt][nt]
    #pragma unroll
    for (int mt = 0; mt < 4; ++mt)
        #pragma unroll
        for (int nt = 0; nt < 4; ++nt) acc[mt][nt] = (f32x4)0.0f;

    // GEMM1: one K=32 step; B = rbfᵀ from LDS (contiguous b128)
    #pragma unroll
    for (int nt = 0; nt < 4; ++nt) {
        short8 bfr = *(const short8*)(sm + SM_RBF + (nt * 16 + l15) * 64 + l4 * 16);
        #pragma unroll
        for (int mt = 0; mt < 4; ++mt)
            acc[mt][nt] = __builtin_amdgcn_mfma_f32_16x16x32_bf16(a1[mt], bfr, acc[mt][nt], 0, 0, 0);
    }

    // silu -> hid[edge][hidcol] bf16, b64 stores (4 consecutive cols/thread)
    #pragma unroll
    for (int mt = 0; mt < 4; ++mt) {
        const int hc0 = w * 64 + mt * 16 + l4 * 4;
        #pragma unroll
        for (int nt = 0; nt < 4; ++nt) {
            const int row = nt * 16 + l15;
            unsigned int pk0 = cvt_pk(silu_f(acc[mt][nt][0]), silu_f(acc[mt][nt][1]));
            unsigned int pk1 = cvt_pk(silu_f(acc[mt][nt][2]), silu_f(acc[mt][nt][3]));
            *(uint2*)(sm + SM_HID + row * 512 +
                      (((hc0 >> 3) ^ (row & 7)) << 4) + (hc0 & 7) * 2) =
                make_uint2(pk0, pk1);
        }
    }
    __syncthreads();

    // GEMM2: filtᵀ = Wf2ᵀ·hiddenᵀ; B from LDS (contiguous b128, swizzled)
    #pragma unroll
    for (int mt = 0; mt < 4; ++mt)
        #pragma unroll
        for (int nt = 0; nt < 4; ++nt) acc[mt][nt] = (f32x4)0.0f;

    for (int ks = 0; ks < 8; ++ks) {
        short8 anext[4];
        if (ks < 7) {
            #pragma unroll
            for (int mt = 0; mt < 4; ++mt)
                anext[mt] = *(const short8*)(P2 + (((ks + 1) * 16 + 4 * w + mt) * 64 + l) * 8);
        }
        #pragma unroll
        for (int nt = 0; nt < 4; ++nt) {
            const int row = nt * 16 + l15;
            short8 bfh = *(const short8*)(sm + SM_HID + row * 512 +
                            ((((ks << 2) + l4) ^ (row & 7)) << 4));
            #pragma unroll
            for (int mt = 0; mt < 4; ++mt)
                acc[mt][nt] = __builtin_amdgcn_mfma_f32_16x16x32_bf16(acur[mt], bfh, acc[mt][nt], 0, 0, 0);
        }
        if (ks < 7) {
            #pragma unroll
            for (int mt = 0; mt < 4; ++mt) acur[mt] = anext[mt];
        }
    }
    __syncthreads();   // hid region free -> msg overlay

    f32x4 bc4[4];
    #pragma unroll
    for (int mt = 0; mt < 4; ++mt)
        bc4[mt] = *(const f32x4*)(bf2 + w * 64 + mt * 16 + l4 * 4);

    const float* xbase[4];
    #pragma unroll
    for (int nt = 0; nt < 4; ++nt)
        xbase[nt] = x + (size_t)col_s[nt * 16 + l15] * HDIM;

    float sum = 0.0f;
    int cur = nid_s[0];

    #pragma unroll
    for (int ms = 0; ms < 2; ++ms) {
        #pragma unroll
        for (int ni = 0; ni < 2; ++ni) {
            const int nt  = ms * 2 + ni;
            const int pos = ni * 16 + l15;
            #pragma unroll
            for (int mt = 0; mt < 4; ++mt) {
                const int fc0 = w * 64 + mt * 16 + l4 * 4;
                f32x4 xv = *(const f32x4*)(xbase[nt] + fc0);
                f32x4 mv = (acc[mt][nt] + bc4[mt]) * xv;
                *(f32x4*)(sm + SM_HID + pos * 1024 +
                          (((fc0 >> 2) ^ (pos & 7)) << 4)) = mv;
            }
        }
        __syncthreads();
        for (int pos = 0; pos < 32; ++pos) {
            const int row = ms * 32 + pos;
            const int nid = nid_s[row];
            float v = *(const float*)(sm + SM_HID + pos * 1024 +
                        (((t >> 2) ^ (pos & 7)) << 4) + (t & 3) * 4);
            if (nid != cur) {
                atomicAdd(&agg[(size_t)cur * HDIM + t], sum);
                sum = 0.0f; cur = nid;
            }
            sum += v;
        }
        __syncthreads();
    }
    atomicAdd(&agg[(size_t)cur * HDIM + t], sum);
}

// ---------------------------------------------------------------------------
// Node kernel: both GEMMs swapped (midᵀ, hᵀ): vectorized staging, b64 mid
// stores, float4 hout stores, fused BN partials.
// ---------------------------------------------------------------------------
__global__ __launch_bounds__(256, 3) void node_kernel(
    const float* __restrict__ agg, const float* __restrict__ bu1,
    const float* __restrict__ bu2,
    const unsigned short* __restrict__ Pu1, const unsigned short* __restrict__ Pu2,
    float* __restrict__ hout, float* __restrict__ sums)
{
    __shared__ char sm[32768];    // [64 nodes][256] bf16, XOR-swizzled
    const int t  = threadIdx.x;
    const int r0 = blockIdx.x * 64;
    const int l = t & 63, w = t >> 6;
    const int l15 = l & 15, l4 = l >> 4;

    // stage agg -> LDS bf16 (float4 + cvt_pk + b64)
    {
        const int row = t & 63, q = t >> 6;
        const bool valid = (r0 + row) < N_NODES;
        const float4* src = (const float4*)(agg + (size_t)(r0 + row) * HDIM) + q * 16;
        #pragma unroll
        for (int i = 0; i < 16; ++i) {
            float4 v = valid ? src[i] : make_float4(0.f, 0.f, 0.f, 0.f);
            const int c0 = q * 64 + i * 4;
            *(uint2*)(sm + row * 512 + (((c0 >> 3) ^ (row & 7)) << 4) + (c0 & 7) * 2) =
                make_uint2(cvt_pk(v.x, v.y), cvt_pk(v.z, v.w));
        }
    }

    short8 acur[4];
    #pragma unroll
    for (int mt = 0; mt < 4; ++mt)
        acur[mt] = *(const short8*)(Pu1 + ((4 * w + mt) * 64 + l) * 8);

    __syncthreads();

    f32x4 acc[4][4];
    #pragma unroll
    for (int mt = 0; mt < 4; ++mt)
        #pragma unroll
        for (int nt = 0; nt < 4; ++nt) acc[mt][nt] = (f32x4)0.0f;

    // GEMM1': midᵀ = Wu1ᵀ·aggᵀ
    for (int ks = 0; ks < 8; ++ks) {
        short8 anext[4];
        if (ks < 7) {
            #pragma unroll
            for (int mt = 0; mt < 4; ++mt)
                anext[mt] = *(const short8*)(Pu1 + (((ks + 1) * 16 + 4 * w + mt) * 64 + l) * 8);
        }
        #pragma unroll
        for (int nt = 0; nt < 4; ++nt) {
            const int row = nt * 16 + l15;
            short8 bfa = *(const short8*)(sm + row * 512 +
                            ((((ks << 2) + l4) ^ (row & 7)) << 4));
            #pragma unroll
            for (int mt = 0; mt < 4; ++mt)
                acc[mt][nt] = __builtin_amdgcn_mfma_f32_16x16x32_bf16(acur[mt], bfa, acc[mt][nt], 0, 0, 0);
        }
        if (ks < 7) {
            #pragma unroll
            for (int mt = 0; mt < 4; ++mt) acur[mt] = anext[mt];
        }
    }
    __syncthreads();   // all reads done; overwrite with mid

    #pragma unroll
    for (int mt = 0; mt < 4; ++mt)
        acur[mt] = *(const short8*)(Pu2 + ((4 * w + mt) * 64 + l) * 8);

    // mid = silu(acc + bu1) -> LDS (b64 stores, 4 consecutive cols)
    #pragma unroll
    for (int mt = 0; mt < 4; ++mt) {
        const int mc0 = w * 64 + mt * 16 + l4 * 4;
        f32x4 b4 = *(const f32x4*)(bu1 + mc0);
        #pragma unroll
        for (int nt = 0; nt < 4; ++nt) {
            const int row = nt * 16 + l15;
            unsigned int pk0 = cvt_pk(silu_f(acc[mt][nt][0] + b4[0]), silu_f(acc[mt][nt][1] + b4[1]));
            unsigned int pk1 = cvt_pk(silu_f(acc[mt][nt][2] + b4[2]), silu_f(acc[mt][nt][3] + b4[3]));
            *(uint2*)(sm + row * 512 + (((mc0 >> 3) ^ (row & 7)) << 4) + (mc0 & 7) * 2) =
                make_uint2(pk0, pk1);
            acc[mt][nt] = (f32x4)0.0f;
        }
    }
    __syncthreads();

    // GEMM2': hᵀ = Wu2ᵀ·midᵀ
    for (int ks = 0; ks < 8; ++ks) {
        short8 anext[4];
        if (ks < 7) {
            #pragma unroll
            for (int mt = 0; mt < 4; ++mt)
                anext[mt] = *(const short8*)(Pu2 + (((ks + 1) * 16 + 4 * w + mt) * 64 + l) * 8);
        }
        #pragma unroll
        for (int nt = 0; nt < 4; ++nt) {
            const int row = nt * 16 + l15;
            short8 bfm = *(const short8*)(sm + row * 512 +
                            ((((ks << 2) + l4) ^ (row & 7)) << 4));
            #pragma unroll
            for (int mt = 0; mt < 4; ++mt)
                acc[mt][nt] = __builtin_amdgcn_mfma_f32_16x16x32_bf16(acur[mt], bfm, acc[mt][nt], 0, 0, 0);
        }
        if (ks < 7) {
            #pragma unroll
            for (int mt = 0; mt < 4; ++mt) acur[mt] = anext[mt];
        }
    }

    // epilogue: float4 h stores + BN partials
    #pragma unroll
    for (int mt = 0; mt < 4; ++mt) {
        const int hc0 = w * 64 + mt * 16 + l4 * 4;
        f32x4 b4 = *(const f32x4*)(bu2 + hc0);
        f32x4 s = (f32x4)0.0f, s2 = (f32x4)0.0f;
        #pragma unroll
        for (int nt = 0; nt < 4; ++nt) {
            const int gr = r0 + nt * 16 + l15;
            if (gr < N_NODES) {
                f32x4 hv = acc[mt][nt] + b4;
                *(f32x4*)(hout + (size_t)gr * HDIM + hc0) = hv;
                s += hv; s2 += hv * hv;
            }
        }
        #pragma unroll
        for (int off = 1; off < 16; off <<= 1) {
            #pragma unroll
            for (int r = 0; r < 4; ++r) {
                s[r]  += __shfl_xor(s[r], off);
                s2[r] += __shfl_xor(s2[r], off);
            }
        }
        if (l15 == 0) {
            #pragma unroll
            for (int r = 0; r < 4; ++r) {
                atomicAdd(&sums[hc0 + r], s[r]);
                atomicAdd(&sums[HDIM + hc0 + r], s2[r]);
            }
        }
    }
}

// ---------------------------------------------------------------------------
__global__ __launch_bounds__(256) void final_kernel(
    const float* __restrict__ x, const float* __restrict__ sums,
    const float* __restrict__ gamma, const float* __restrict__ beta,
    float* __restrict__ out)
{
    const int i = blockIdx.x * 256 + threadIdx.x;
    const int j = i & (HDIM - 1);
    const float mean = sums[j] * (1.0f / N_NODES);
    const float var  = sums[HDIM + j] * (1.0f / N_NODES) - mean * mean;
    const float inv  = rsqrtf(var + BN_EPS);
    const float hv   = out[i];
    out[i] = x[i] + gamma[j] * (hv - mean) * inv + beta[j];
}

extern "C" void kernel_launch(void* const* d_in, const int* in_sizes, int n_in,
                              void* d_out, int out_size, void* d_ws, size_t ws_size,
                              hipStream_t stream) {
    const float* x     = (const float*)d_in[0];
    const float* rbf   = (const float*)d_in[1];
    const int*   ei    = (const int*)d_in[2];
    const float* Wf1   = (const float*)d_in[3];
    const float* bf1   = (const float*)d_in[4];
    const float* Wf2   = (const float*)d_in[5];
    const float* bf2   = (const float*)d_in[6];
    const float* Wu1   = (const float*)d_in[7];
    const float* bu1   = (const float*)d_in[8];
    const float* Wu2   = (const float*)d_in[9];
    const float* bu2   = (const float*)d_in[10];
    const float* gamma = (const float*)d_in[11];
    const float* beta  = (const float*)d_in[12];
    float* out = (float*)d_out;

    char* ws = (char*)d_ws;
    float* agg     = (float*)(ws);                            // 10,240,000 B
    float* sums    = (float*)(ws + 10240000);                 // 2,048 B
    int*   cnt     = (int*)(ws + 10242048);                   // 40,960 B
    int*   perm    = (int*)(ws + 10283008);                   // 1,280,000 B
    int*   nodepos = (int*)(ws + 11563008);                   // 1,280,000 B
    unsigned short* Pf2 = (unsigned short*)(ws + 12843008);   // 131,072 B
    unsigned short* Pu1 = (unsigned short*)(ws + 12974080);   // 131,072 B
    unsigned short* Pu2 = (unsigned short*)(ws + 13105152);   // 131,072 B
    unsigned short* P1  = (unsigned short*)(ws + 13236224);   // 16,384 B

    // one memset covers agg + sums + cnt (contiguous)
    hipMemsetAsync(agg, 0, 10283008, stream);

    prep_kernel<<<dim3(256, 4), 256, 0, stream>>>(Wf2, Wu1, Wu2, Wf1, bf1,
                                                  Pf2, Pu1, Pu2, P1);
    hist_kernel<<<E_EDGES / 256, 256, 0, stream>>>(ei, cnt);
    scan_kernel<<<1, 256, 0, stream>>>(cnt);
    fill_kernel<<<E_EDGES / 256, 256, 0, stream>>>(ei, cnt, perm, nodepos);

    edge_kernel<<<E_EDGES / 64, 256, 0, stream>>>(
        rbf, ei + E_EDGES, perm, nodepos, P1, Pf2, bf2, x, agg);
    node_kernel<<<(N_NODES + 63) / 64, 256, 0, stream>>>(
        agg, bu1, bu2, Pu1, Pu2, out, sums);
    final_kernel<<<(N_NODES * HDIM) / 256, 256, 0, stream>>>(x, sums, gamma, beta, out);
}